// Round 17
// baseline (346.858 us; speedup 1.0000x reference)
//
#include <hip/hip_runtime.h>
#include <math.h>

// Shapes: B=8, N_L=256, C=256, NH=8, HD=32, H=W=64, N_C=4096, L=3, KS={3,5,7}
// Reference reshape semantics: v[b][m][dim] with m = c*16 + (hw>>8), dim = hw&255.

namespace {

constexpr float CSCALE = 0.17677669529663688f;

typedef __attribute__((ext_vector_type(8))) __bf16 bf16x8;
typedef __attribute__((ext_vector_type(4))) float f32x4;

__device__ __forceinline__ float gelu_f(float x) {
  return 0.5f * x * (1.0f + erff(x * 0.70710678118654752f));
}

__device__ __forceinline__ unsigned short f2bf(float f) {
  union { float f; unsigned u; } v; v.f = f;
  unsigned r = v.u + 0x7fffu + ((v.u >> 16) & 1u);  // RNE
  return (unsigned short)(r >> 16);
}

__device__ __forceinline__ float bf2f(unsigned short u) {
  union { unsigned u; float f; } v; v.u = (unsigned)u << 16;
  return v.f;
}

__device__ __forceinline__ bf16x8 pack8(float4 a, float4 b) {
  union { unsigned short u[8]; bf16x8 v; } A;
  A.u[0] = f2bf(a.x); A.u[1] = f2bf(a.y); A.u[2] = f2bf(a.z); A.u[3] = f2bf(a.w);
  A.u[4] = f2bf(b.x); A.u[5] = f2bf(b.y); A.u[6] = f2bf(b.z); A.u[7] = f2bf(b.w);
  return A.v;
}

// ---------------------------------------------------------------------------
// Cast fp32 -> bf16 for the 5 weight matrices. grid = 81.
// ---------------------------------------------------------------------------
__global__ __launch_bounds__(256) void cast_w(
    const float* __restrict__ qw, const float* __restrict__ kw,
    const float* __restrict__ fw, const float* __restrict__ hww,
    const float* __restrict__ pw,
    unsigned short* qwb, unsigned short* kwb, unsigned short* fwb,
    unsigned short* hwb, unsigned short* pwb) {
  const int blk = blockIdx.x;
  const float* s; unsigned short* d; int b0, nq;
  if      (blk < 16) { s = qw;  d = qwb; b0 = blk;      nq = 16384; }
  else if (blk < 32) { s = kw;  d = kwb; b0 = blk - 16; nq = 16384; }
  else if (blk < 49) { s = fw;  d = fwb; b0 = blk - 32; nq = 16640; }
  else if (blk < 65) { s = hww; d = hwb; b0 = blk - 49; nq = 16384; }
  else               { s = pw;  d = pwb; b0 = blk - 65; nq = 16384; }
  #pragma unroll
  for (int t = 0; t < 4; ++t) {
    const int q = b0*1024 + t*256 + threadIdx.x;
    if (q < nq) {
      float4 v = ((const float4*)s)[q];
      ushort4 o;
      o.x = f2bf(v.x); o.y = f2bf(v.y); o.z = f2bf(v.z); o.w = f2bf(v.w);
      ((ushort4*)d)[q] = o;
    }
  }
}

// ---------------------------------------------------------------------------
// MERGED q/k/f projections (one launch, 1056 blocks), bf16 weights.
// ---------------------------------------------------------------------------
__global__ __launch_bounds__(256) void fused_qkf(
    const float* __restrict__ lat, const float* __restrict__ ctx,
    const unsigned short* __restrict__ qw, const unsigned short* __restrict__ kw,
    const unsigned short* __restrict__ fw, const float* __restrict__ fb,
    unsigned short* __restrict__ q_bf, unsigned short* __restrict__ kpl,
    unsigned short* __restrict__ vctx, float* __restrict__ gates) {
  __shared__ unsigned short sh[256 * 68];   // 34 KB (f); k uses [64*264] of it
  const int blk = blockIdx.x;
  const int tid = threadIdx.x, w = tid >> 6, l = tid & 63;
  const int lr = l & 15, lk = l >> 4;

  if (blk < 32) {
    // ---------------- q projection ----------------
    const int r0 = blk * 64, rw = r0 + w*16;
    const float* ap = lat + (size_t)(rw + lr)*256 + lk*8;
    f32x4 acc[16];
    #pragma unroll
    for (int j = 0; j < 16; ++j) acc[j] = (f32x4){0.f,0.f,0.f,0.f};
    #pragma unroll
    for (int k0 = 0; k0 < 256; k0 += 32) {
      bf16x8 a = pack8(*(const float4*)(ap + k0), *(const float4*)(ap + k0 + 4));
      #pragma unroll
      for (int j = 0; j < 16; ++j) {
        bf16x8 b = *reinterpret_cast<const bf16x8*>(qw + (size_t)(j*16 + lr)*256 + k0 + lk*8);
        acc[j] = __builtin_amdgcn_mfma_f32_16x16x32_bf16(a, b, acc[j], 0, 0, 0);
      }
    }
    #pragma unroll
    for (int j = 0; j < 16; ++j)
      #pragma unroll
      for (int rr = 0; rr < 4; ++rr)
        q_bf[(size_t)(rw + lk*4 + rr)*256 + j*16 + lr] = f2bf(acc[j][rr]);
  } else if (blk < 544) {
    // ---------------- k projection (head-planar out) ----------------
    const int r0 = (blk - 32) * 64, rw = r0 + w*16;
    const float* ap = ctx + (size_t)(rw + lr)*256 + lk*8;
    f32x4 acc[16];
    #pragma unroll
    for (int j = 0; j < 16; ++j) acc[j] = (f32x4){0.f,0.f,0.f,0.f};
    #pragma unroll
    for (int k0 = 0; k0 < 256; k0 += 32) {
      bf16x8 a = pack8(*(const float4*)(ap + k0), *(const float4*)(ap + k0 + 4));
      #pragma unroll
      for (int j = 0; j < 16; ++j) {
        bf16x8 b = *reinterpret_cast<const bf16x8*>(kw + (size_t)(j*16 + lr)*256 + k0 + lk*8);
        acc[j] = __builtin_amdgcn_mfma_f32_16x16x32_bf16(a, b, acc[j], 0, 0, 0);
      }
    }
    #pragma unroll
    for (int j = 0; j < 16; ++j)
      #pragma unroll
      for (int rr = 0; rr < 4; ++rr)
        sh[(w*16 + lk*4 + rr)*264 + j*16 + lr] = f2bf(acc[j][rr]);
    __syncthreads();
    const int b = r0 >> 12, mm0 = r0 & 4095;
    #pragma unroll
    for (int it = 0; it < 8; ++it) {
      const int idx = it*256 + tid;
      const int ch = idx & 3, m = (idx >> 2) & 63, h = idx >> 8;
      uint4 v = *(const uint4*)&sh[m*264 + h*32 + ch*8];
      *(uint4*)&kpl[(((size_t)(b*8 + h))*4096 + mm0 + m)*32 + ch*8] = v;
    }
  } else {
    // ---------------- f projection ----------------
    const int r0 = (blk - 544) * 64, rw = r0 + w*16;
    const float* ap = ctx + (size_t)(rw + lr)*256 + lk*8;
    f32x4 acc[17];
    #pragma unroll
    for (int j = 0; j < 17; ++j) acc[j] = (f32x4){0.f,0.f,0.f,0.f};
    #pragma unroll
    for (int k0 = 0; k0 < 256; k0 += 32) {
      bf16x8 a = pack8(*(const float4*)(ap + k0), *(const float4*)(ap + k0 + 4));
      #pragma unroll
      for (int j = 0; j < 17; ++j) {
        const int n = j*16 + lr;
        bf16x8 b = {};
        if (n < 260)
          b = *reinterpret_cast<const bf16x8*>(fw + (size_t)n*256 + k0 + lk*8);
        acc[j] = __builtin_amdgcn_mfma_f32_16x16x32_bf16(a, b, acc[j], 0, 0, 0);
      }
    }
    const int hwl = w*16 + lk*4;
    #pragma unroll
    for (int j = 0; j < 16; ++j) {
      const float bb = fb[j*16 + lr];
      #pragma unroll
      for (int rr = 0; rr < 4; ++rr)
        sh[(j*16 + lr)*68 + hwl + rr] = f2bf(acc[j][rr] + bb);
    }
    {
      const int rbase = rw + lk*4;
      const int b = rbase >> 12, hw = rbase & 4095;
      if (lr < 4) {
        const float bb = fb[256 + lr];
        float4 o = make_float4(acc[16][0] + bb, acc[16][1] + bb,
                               acc[16][2] + bb, acc[16][3] + bb);
        *(float4*)&gates[((size_t)(b*4 + lr))*4096 + hw] = o;
      }
    }
    __syncthreads();
    const int b = r0 >> 12, hw0 = r0 & 4095;
    #pragma unroll
    for (int it = 0; it < 8; ++it) {
      const int idx = it*256 + tid;
      const int n = idx >> 3, ch = idx & 7;
      uint4 v = *(const uint4*)&sh[n*68 + ch*8];
      *(uint4*)&vctx[((size_t)(b*256 + n))*4096 + hw0 + ch*8] = v;
    }
  }
}

// ---------------------------------------------------------------------------
// FUSED depthwise conv chain, sliding-window form; bf16 in/out, in-place.
// grid = 2048.
// ---------------------------------------------------------------------------
__global__ __launch_bounds__(256) void fused_conv(
    const unsigned short* in, const float* __restrict__ wk3,
    const float* __restrict__ wk5, const float* __restrict__ wk7,
    const float* __restrict__ gates, unsigned short* out) {
  constexpr int TW = 70;
  __shared__ float A[TW * TW];
  __shared__ float w3[9];
  __shared__ float w5[25];
  __shared__ float w7[49];
  __shared__ float red[4];
  const int tid = threadIdx.x;
  const int b = blockIdx.x >> 8, c = blockIdx.x & 255;
  if (tid < 9)  w3[tid] = wk3[c*9  + tid];
  else if (tid < 34) w5[tid-9]  = wk5[c*25 + tid-9];
  else if (tid < 83) w7[tid-34] = wk7[c*49 + tid-34];
  const unsigned short* ip = in + (size_t)(b*256 + c) * 4096;
  for (int idx = tid; idx < TW*TW; idx += 256) {
    const int ty = idx / TW, tx = idx - ty*TW;
    const int gy = ty - 3, gx = tx - 3;
    A[idx] = (gy >= 0 && gy < 64 && gx >= 0 && gx < 64) ? bf2f(ip[gy*64 + gx]) : 0.0f;
  }
  __syncthreads();
  const int x = tid & 63, ys = (tid >> 6) * 16;
  const float* g0 = gates + (size_t)(b*4 + 0) * 4096;
  const float* g1 = gates + (size_t)(b*4 + 1) * 4096;
  const float* g2 = gates + (size_t)(b*4 + 2) * 4096;
  const float* g3 = gates + (size_t)(b*4 + 3) * 4096;
  float s[16], acc[16];
  // ---- conv3 (off=2) ----
  #pragma unroll
  for (int i = 0; i < 16; ++i) s[i] = 0.f;
  #pragma unroll
  for (int kx = 0; kx < 3; ++kx) {
    const float* col = &A[(ys + 2)*TW + x + 2 + kx];
    #pragma unroll
    for (int r = 0; r < 18; ++r) {
      const float v = col[r*TW];
      #pragma unroll
      for (int ky = 0; ky < 3; ++ky) {
        const int i = r - ky;
        if (i >= 0 && i < 16) s[i] += w3[ky*3 + kx] * v;
      }
    }
  }
  #pragma unroll
  for (int i = 0; i < 16; ++i) {
    s[i] = gelu_f(s[i]);
    acc[i] = s[i] * g0[(ys + i)*64 + x];
  }
  __syncthreads();
  #pragma unroll
  for (int i = 0; i < 16; ++i) A[(ys + i + 3)*TW + x + 3] = s[i];
  __syncthreads();
  // ---- conv5 (off=1) ----
  #pragma unroll
  for (int i = 0; i < 16; ++i) s[i] = 0.f;
  #pragma unroll
  for (int kx = 0; kx < 5; ++kx) {
    const float* col = &A[(ys + 1)*TW + x + 1 + kx];
    #pragma unroll
    for (int r = 0; r < 20; ++r) {
      const float v = col[r*TW];
      #pragma unroll
      for (int ky = 0; ky < 5; ++ky) {
        const int i = r - ky;
        if (i >= 0 && i < 16) s[i] += w5[ky*5 + kx] * v;
      }
    }
  }
  #pragma unroll
  for (int i = 0; i < 16; ++i) {
    s[i] = gelu_f(s[i]);
    acc[i] += s[i] * g1[(ys + i)*64 + x];
  }
  __syncthreads();
  #pragma unroll
  for (int i = 0; i < 16; ++i) A[(ys + i + 3)*TW + x + 3] = s[i];
  __syncthreads();
  // ---- conv7 (off=0) + mean ----
  #pragma unroll
  for (int i = 0; i < 16; ++i) s[i] = 0.f;
  #pragma unroll
  for (int kx = 0; kx < 7; ++kx) {
    const float* col = &A[ys*TW + x + kx];
    #pragma unroll
    for (int r = 0; r < 22; ++r) {
      const float v = col[r*TW];
      #pragma unroll
      for (int ky = 0; ky < 7; ++ky) {
        const int i = r - ky;
        if (i >= 0 && i < 16) s[i] += w7[ky*7 + kx] * v;
      }
    }
  }
  float msum = 0.f;
  #pragma unroll
  for (int i = 0; i < 16; ++i) {
    s[i] = gelu_f(s[i]);
    acc[i] += s[i] * g2[(ys + i)*64 + x];
    msum += s[i];
  }
  #pragma unroll
  for (int off = 32; off >= 1; off >>= 1) msum += __shfl_xor(msum, off, 64);
  if ((tid & 63) == 0) red[tid >> 6] = msum;
  __syncthreads();
  const float vg = gelu_f((red[0]+red[1]+red[2]+red[3]) * (1.0f/4096.0f));
  unsigned short* vp = out + (size_t)(b*256 + c) * 4096;
  #pragma unroll
  for (int i = 0; i < 16; ++i) {
    const int pix = (ys + i)*64 + x;
    vp[pix] = f2bf(acc[i] + vg * g3[pix]);
  }
}

// ---------------------------------------------------------------------------
// Full-depth MFMA h-GEMM (bf16 weights). grid (64, 8).
// ---------------------------------------------------------------------------
__global__ __launch_bounds__(256) void mfma_h(
    const unsigned short* __restrict__ vall, const unsigned short* __restrict__ hwb,
    const float* __restrict__ hb, unsigned short* __restrict__ vlin) {
  __shared__ unsigned short sh[256 * 72];
  const int hw0 = blockIdx.x * 64, b = blockIdx.y;
  const int tid = threadIdx.x, w = tid >> 6, l = tid & 63;
  const int lr = l & 15, lk = l >> 4;
  const int cl = tid >> 3, hl = (tid & 7) * 8;
  #pragma unroll
  for (int c0 = 0; c0 < 256; c0 += 32) {
    const unsigned short* sp = vall + (size_t)(b*256 + c0 + cl)*4096 + hw0 + hl;
    ushort4 u0 = *(const ushort4*)sp;
    ushort4 u1 = *(const ushort4*)(sp + 4);
    sh[(hl+0)*264 + c0+cl] = u0.x; sh[(hl+1)*264 + c0+cl] = u0.y;
    sh[(hl+2)*264 + c0+cl] = u0.z; sh[(hl+3)*264 + c0+cl] = u0.w;
    sh[(hl+4)*264 + c0+cl] = u1.x; sh[(hl+5)*264 + c0+cl] = u1.y;
    sh[(hl+6)*264 + c0+cl] = u1.z; sh[(hl+7)*264 + c0+cl] = u1.w;
  }
  __syncthreads();
  const int dw = w * 64;
  f32x4 acc[4][4];
  #pragma unroll
  for (int j2 = 0; j2 < 4; ++j2)
    #pragma unroll
    for (int j = 0; j < 4; ++j) acc[j2][j] = (f32x4){0.f,0.f,0.f,0.f};
  #pragma unroll
  for (int k0 = 0; k0 < 256; k0 += 32) {
    bf16x8 a[4];
    #pragma unroll
    for (int j2 = 0; j2 < 4; ++j2)
      a[j2] = *reinterpret_cast<const bf16x8*>(hwb + (size_t)(dw + j2*16 + lr)*256 + k0 + lk*8);
    #pragma unroll
    for (int j = 0; j < 4; ++j) {
      bf16x8 bv = *reinterpret_cast<const bf16x8*>(&sh[(j*16 + lr)*264 + k0 + lk*8]);
      #pragma unroll
      for (int j2 = 0; j2 < 4; ++j2)
        acc[j2][j] = __builtin_amdgcn_mfma_f32_16x16x32_bf16(a[j2], bv, acc[j2][j], 0, 0, 0);
    }
  }
  float hbv[4][4];
  #pragma unroll
  for (int j2 = 0; j2 < 4; ++j2)
    #pragma unroll
    for (int rr = 0; rr < 4; ++rr) hbv[j2][rr] = hb[dw + j2*16 + lk*4 + rr];
  __syncthreads();
  #pragma unroll
  for (int j2 = 0; j2 < 4; ++j2)
    #pragma unroll
    for (int j = 0; j < 4; ++j)
      #pragma unroll
      for (int rr = 0; rr < 4; ++rr)
        sh[(dw + j2*16 + lk*4 + rr)*72 + j*16 + lr] = f2bf(acc[j2][j][rr] + hbv[j2][rr]);
  __syncthreads();
  const int q = hw0 >> 8, dim0 = hw0 & 255;
  #pragma unroll
  for (int it = 0; it < 8; ++it) {
    const int dl = it*32 + (tid >> 3);
    const int ch = tid & 7;
    const int m = dl*16 + q;
    uint4 v = *(const uint4*)&sh[dl*72 + ch*8];
    *(uint4*)&vlin[((size_t)(b*4096 + m))*256 + dim0 + ch*8] = v;
  }
}

// ---------------------------------------------------------------------------
// bf16 transpose: v_tb[b][dim][m] from vlin[b][m][dim]. grid (64, 4, 8).
// ---------------------------------------------------------------------------
__global__ __launch_bounds__(256) void trans_bf(
    const unsigned short* __restrict__ vlin, unsigned short* __restrict__ vt) {
  __shared__ unsigned short T[64][72];
  const int tid = threadIdx.x;
  const int m0 = blockIdx.x * 64, d0 = blockIdx.y * 64, b = blockIdx.z;
  #pragma unroll
  for (int it = 0; it < 2; ++it) {
    const int ml = it*32 + (tid >> 3);
    const int ch = tid & 7;
    uint4 v = *(const uint4*)&vlin[((size_t)(b*4096 + m0 + ml))*256 + d0 + ch*8];
    *(uint4*)&T[ml][ch*8] = v;
  }
  __syncthreads();
  #pragma unroll
  for (int it = 0; it < 2; ++it) {
    const int dl = it*32 + (tid >> 3);
    const int ch = tid & 7;
    unsigned short tmp[8];
    #pragma unroll
    for (int k = 0; k < 8; ++k) tmp[k] = T[ch*8 + k][dl];
    *(uint4*)&vt[((size_t)(b*256 + d0 + dl))*4096 + m0 + ch*8] = *(uint4*)tmp;
  }
}

// ---------------------------------------------------------------------------
// FUSED attention + PV; K head-planar kpl[b][h][m][32]; nt attn stores.
// R17: QBLK=32 — each block handles 32 q-rows (2 Q fragments/lane), so every
// K/V fragment load feeds 2 MFMAs (2x arithmetic intensity, half the K read
// traffic). grid = 512 (bh = blk & 63). LDS ~45 KB -> 2 blocks/CU (grid-bound).
// ---------------------------------------------------------------------------
__global__ __launch_bounds__(256) void attn_pv(
    const unsigned short* __restrict__ qb, const unsigned short* __restrict__ kpl,
    const unsigned short* __restrict__ vt, float* __restrict__ attn,
    unsigned short* __restrict__ aout) {
  const int blk = blockIdx.x;
  const int bh = blk & 63, nt = blk >> 6;
  const int b = bh >> 3, h = bh & 7;
  const int tid = threadIdx.x;
  const int w = tid >> 6, l = tid & 63;
  const int lr = l & 15, lk = l >> 4;
  const int n0 = nt * 32;
  __shared__ float rs[4][32];
  __shared__ unsigned short pl[4][32][40];
  __shared__ float ps[4][32][36];
  __shared__ float osum[4][32][32];
  bf16x8 aq0 = *reinterpret_cast<const bf16x8*>(
      qb + ((size_t)(b*256 + n0 + lr))*256 + h*32 + lk*8);
  bf16x8 aq1 = *reinterpret_cast<const bf16x8*>(
      qb + ((size_t)(b*256 + n0 + 16 + lr))*256 + h*32 + lk*8);
  const unsigned short* kbase = kpl + ((size_t)(b*8 + h))*4096*32 + lk*8;
  // pass 1: row sums (8 rows per thread-quad via two D frags)
  float sum0[4] = {0.f,0.f,0.f,0.f}, sum1[4] = {0.f,0.f,0.f,0.f};
  #pragma unroll 4
  for (int mt = 0; mt < 64; ++mt) {
    const int m0 = w*1024 + mt*16;
    bf16x8 bk = *reinterpret_cast<const bf16x8*>(kbase + (size_t)(m0 + lr)*32);
    f32x4 d0 = __builtin_amdgcn_mfma_f32_16x16x32_bf16(aq0, bk, (f32x4){0.f,0.f,0.f,0.f}, 0, 0, 0);
    f32x4 d1 = __builtin_amdgcn_mfma_f32_16x16x32_bf16(aq1, bk, (f32x4){0.f,0.f,0.f,0.f}, 0, 0, 0);
    #pragma unroll
    for (int r = 0; r < 4; ++r) {
      sum0[r] += __expf(d0[r] * CSCALE);
      sum1[r] += __expf(d1[r] * CSCALE);
    }
  }
  #pragma unroll
  for (int r = 0; r < 4; ++r) {
    #pragma unroll
    for (int m = 1; m < 16; m <<= 1) {
      sum0[r] += __shfl_xor(sum0[r], m, 64);
      sum1[r] += __shfl_xor(sum1[r], m, 64);
    }
  }
  if (lr == 0) {
    #pragma unroll
    for (int r = 0; r < 4; ++r) {
      rs[w][lk*4 + r]      = sum0[r];
      rs[w][16 + lk*4 + r] = sum1[r];
    }
  }
  __syncthreads();
  float invS0[4], invS1[4];
  #pragma unroll
  for (int r = 0; r < 4; ++r) {
    const int ri = lk*4 + r;
    invS0[r] = 1.0f / (rs[0][ri] + rs[1][ri] + rs[2][ri] + rs[3][ri]);
    invS1[r] = 1.0f / (rs[0][16+ri] + rs[1][16+ri] + rs[2][16+ri] + rs[3][16+ri]);
  }
  // pass 2: paired QK (4 MFMA) + staged nt attn store + PV (4 MFMA)
  float* ab = attn + ((size_t)bh*256 + n0) * 4096;
  const unsigned short* vb = vt + ((size_t)(b*256 + h*32))*4096;
  const int fr = l >> 3;          // 0..7
  const int fm = (l & 7) * 4;     // 0..28
  f32x4 acc00 = {0.f,0.f,0.f,0.f}, acc01 = {0.f,0.f,0.f,0.f};
  f32x4 acc10 = {0.f,0.f,0.f,0.f}, acc11 = {0.f,0.f,0.f,0.f};
  #pragma unroll 2
  for (int mt2 = 0; mt2 < 32; ++mt2) {
    const int m0 = w*1024 + mt2*32;
    bf16x8 bk0 = *reinterpret_cast<const bf16x8*>(kbase + (size_t)(m0 + lr)*32);
    bf16x8 bk1 = *reinterpret_cast<const bf16x8*>(kbase + (size_t)(m0 + 16 + lr)*32);
    bf16x8 bv0 = *reinterpret_cast<const bf16x8*>(vb + (size_t)lr*4096 + m0 + lk*8);
    bf16x8 bv1 = *reinterpret_cast<const bf16x8*>(vb + (size_t)(16 + lr)*4096 + m0 + lk*8);
    f32x4 d00 = __builtin_amdgcn_mfma_f32_16x16x32_bf16(aq0, bk0, (f32x4){0.f,0.f,0.f,0.f}, 0, 0, 0);
    f32x4 d01 = __builtin_amdgcn_mfma_f32_16x16x32_bf16(aq0, bk1, (f32x4){0.f,0.f,0.f,0.f}, 0, 0, 0);
    f32x4 d10 = __builtin_amdgcn_mfma_f32_16x16x32_bf16(aq1, bk0, (f32x4){0.f,0.f,0.f,0.f}, 0, 0, 0);
    f32x4 d11 = __builtin_amdgcn_mfma_f32_16x16x32_bf16(aq1, bk1, (f32x4){0.f,0.f,0.f,0.f}, 0, 0, 0);
    #pragma unroll
    for (int r = 0; r < 4; ++r) {
      const int ra = lk*4 + r, rb = 16 + lk*4 + r;
      float p;
      p = __expf(d00[r] * CSCALE) * invS0[r]; ps[w][ra][lr]      = p; pl[w][ra][lr]      = f2bf(p);
      p = __expf(d01[r] * CSCALE) * invS0[r]; ps[w][ra][16 + lr] = p; pl[w][ra][16 + lr] = f2bf(p);
      p = __expf(d10[r] * CSCALE) * invS1[r]; ps[w][rb][lr]      = p; pl[w][rb][lr]      = f2bf(p);
      p = __expf(d11[r] * CSCALE) * invS1[r]; ps[w][rb][16 + lr] = p; pl[w][rb][16 + lr] = f2bf(p);
    }
    bf16x8 pa0 = *reinterpret_cast<const bf16x8*>(&pl[w][lr][lk*8]);
    bf16x8 pa1 = *reinterpret_cast<const bf16x8*>(&pl[w][16 + lr][lk*8]);
    acc00 = __builtin_amdgcn_mfma_f32_16x16x32_bf16(pa0, bv0, acc00, 0, 0, 0);
    acc01 = __builtin_amdgcn_mfma_f32_16x16x32_bf16(pa0, bv1, acc01, 0, 0, 0);
    acc10 = __builtin_amdgcn_mfma_f32_16x16x32_bf16(pa1, bv0, acc10, 0, 0, 0);
    acc11 = __builtin_amdgcn_mfma_f32_16x16x32_bf16(pa1, bv1, acc11, 0, 0, 0);
    #pragma unroll
    for (int i = 0; i < 4; ++i) {
      const int row = i*8 + fr;
      f32x4 pv4 = *(const f32x4*)&ps[w][row][fm];
      __builtin_nontemporal_store(pv4, (f32x4*)&ab[(size_t)row*4096 + m0 + fm]);
    }
  }
  #pragma unroll
  for (int r = 0; r < 4; ++r) {
    osum[w][lk*4 + r][lr]           = acc00[r];
    osum[w][lk*4 + r][16 + lr]      = acc01[r];
    osum[w][16 + lk*4 + r][lr]      = acc10[r];
    osum[w][16 + lk*4 + r][16 + lr] = acc11[r];
  }
  __syncthreads();
  for (int i = tid; i < 1024; i += 256) {
    const int n = i >> 5, d = i & 31;
    const float s = osum[0][n][d] + osum[1][n][d] + osum[2][n][d] + osum[3][n][d];
    aout[((size_t)(b*256 + n0 + n))*256 + h*32 + d] = f2bf(s);
  }
}

// ---------------------------------------------------------------------------
// MFMA proj: out0[r][n] = aout[r][:] . proj_w[n][:] + proj_b[n] (bf16 W).
// grid (32, 4).
// ---------------------------------------------------------------------------
__global__ __launch_bounds__(256) void mfma_proj(
    const unsigned short* __restrict__ A, const unsigned short* __restrict__ W,
    const float* __restrict__ pb, float* __restrict__ out) {
  const int r0 = blockIdx.x * 64, n0 = blockIdx.y * 64;
  const int tid = threadIdx.x, w = tid >> 6, l = tid & 63;
  const int lr = l & 15, lk = l >> 4;
  const int rw = r0 + w*16;
  const unsigned short* ap = A + (size_t)(rw + lr)*256 + lk*8;
  f32x4 acc[4] = {{0.f,0.f,0.f,0.f},{0.f,0.f,0.f,0.f},{0.f,0.f,0.f,0.f},{0.f,0.f,0.f,0.f}};
  #pragma unroll
  for (int k0 = 0; k0 < 256; k0 += 32) {
    bf16x8 a = *reinterpret_cast<const bf16x8*>(ap + k0);
    #pragma unroll
    for (int j = 0; j < 4; ++j) {
      bf16x8 b = *reinterpret_cast<const bf16x8*>(W + (size_t)(n0 + j*16 + lr)*256 + k0 + lk*8);
      acc[j] = __builtin_amdgcn_mfma_f32_16x16x32_bf16(a, b, acc[j], 0, 0, 0);
    }
  }
  #pragma unroll
  for (int j = 0; j < 4; ++j) {
    const int n = n0 + j*16 + lr;
    const float bb = pb[n];
    #pragma unroll
    for (int rr = 0; rr < 4; ++rr)
      out[(size_t)(rw + lk*4 + rr)*256 + n] = acc[j][rr] + bb;
  }
}

} // namespace

extern "C" void kernel_launch(void* const* d_in, const int* in_sizes, int n_in,
                              void* d_out, int out_size, void* d_ws, size_t ws_size,
                              hipStream_t stream) {
  (void)in_sizes; (void)n_in; (void)out_size; (void)ws_size;
  const float* latents = (const float*)d_in[0];
  const float* context = (const float*)d_in[1];
  const float* q_w    = (const float*)d_in[2];
  const float* k_w    = (const float*)d_in[3];
  const float* f_w    = (const float*)d_in[4];
  const float* f_b    = (const float*)d_in[5];
  const float* h_w    = (const float*)d_in[6];
  const float* h_b    = (const float*)d_in[7];
  const float* fk0    = (const float*)d_in[8];
  const float* fk1    = (const float*)d_in[9];
  const float* fk2    = (const float*)d_in[10];
  const float* proj_w = (const float*)d_in[11];
  const float* proj_b = (const float*)d_in[12];

  float* out0 = (float*)d_out;                  // (8,256,256)
  float* attn = out0 + (size_t)8*256*256;       // (8,8,256,4096)

  // workspace layout (byte offsets), total ~70 MB
  char* w = (char*)d_ws;
  unsigned short* vcv     = (unsigned short*)(w + 0x0);        // 16 MB vctx/vall (in-place conv)
  unsigned short* kpl     = (unsigned short*)(w + 0x1000000);  // 16 MB (8,8,4096,32) head-planar K
  unsigned short* v_tb    = (unsigned short*)(w + 0x2000000);  // 16 MB (8,256,4096) vT[dim][m]
  unsigned short* vlin_bf = (unsigned short*)(w + 0x3000000);  // 16 MB (8,4096,256) [m][dim]
  unsigned short* q_bf    = (unsigned short*)(w + 0x4000000);  //  1 MB (8,256,256)
  unsigned short* aout_bf = (unsigned short*)(w + 0x4100000);  //  1 MB
  unsigned short* qw_bf   = (unsigned short*)(w + 0x4200000);  // 128 KB
  unsigned short* kw_bf   = (unsigned short*)(w + 0x4220000);  // 128 KB
  unsigned short* fw_bf   = (unsigned short*)(w + 0x4240000);  // 130 KB
  unsigned short* hw_bf   = (unsigned short*)(w + 0x4270000);  // 128 KB
  unsigned short* pw_bf   = (unsigned short*)(w + 0x4290000);  // 128 KB
  float*          gates   = (float*)(w + 0x42B0000);           // 512 KB fp32

  cast_w    <<<81, 256, 0, stream>>>(q_w, k_w, f_w, h_w, proj_w,
                                     qw_bf, kw_bf, fw_bf, hw_bf, pw_bf);
  fused_qkf <<<1056, 256, 0, stream>>>(latents, context, qw_bf, kw_bf, fw_bf,
                                       f_b, q_bf, kpl, vcv, gates);
  fused_conv<<<2048, 256, 0, stream>>>(vcv, fk0, fk1, fk2, gates, vcv);
  mfma_h    <<<dim3(64, 8), 256, 0, stream>>>(vcv, hw_bf, h_b, vlin_bf);
  trans_bf  <<<dim3(64, 4, 8), 256, 0, stream>>>(vlin_bf, v_tb);
  attn_pv   <<<512, 256, 0, stream>>>(q_bf, kpl, v_tb, attn, aout_bf);
  mfma_proj <<<dim3(32, 4), 256, 0, stream>>>(aout_bf, pw_bf, proj_b, out0);
}

// Round 18
// 330.774 us; speedup vs baseline: 1.0486x; 1.0486x over previous
//
#include <hip/hip_runtime.h>
#include <math.h>

// Shapes: B=8, N_L=256, C=256, NH=8, HD=32, H=W=64, N_C=4096, L=3, KS={3,5,7}
// Reference reshape semantics: v[b][m][dim] with m = c*16 + (hw>>8), dim = hw&255.
// R18 = revert to R15 (best measured, 331 µs): QBLK=16 attn_pv, branchless
// statically-paired pass 2, no explicit prefetch (R16 neutral), no QBLK=32
// (R17 regression: LDS-occupancy loss > intensity gain).

namespace {

constexpr float CSCALE = 0.17677669529663688f;

typedef __attribute__((ext_vector_type(8))) __bf16 bf16x8;
typedef __attribute__((ext_vector_type(4))) float f32x4;

__device__ __forceinline__ float gelu_f(float x) {
  return 0.5f * x * (1.0f + erff(x * 0.70710678118654752f));
}

__device__ __forceinline__ unsigned short f2bf(float f) {
  union { float f; unsigned u; } v; v.f = f;
  unsigned r = v.u + 0x7fffu + ((v.u >> 16) & 1u);  // RNE
  return (unsigned short)(r >> 16);
}

__device__ __forceinline__ float bf2f(unsigned short u) {
  union { unsigned u; float f; } v; v.u = (unsigned)u << 16;
  return v.f;
}

__device__ __forceinline__ bf16x8 pack8(float4 a, float4 b) {
  union { unsigned short u[8]; bf16x8 v; } A;
  A.u[0] = f2bf(a.x); A.u[1] = f2bf(a.y); A.u[2] = f2bf(a.z); A.u[3] = f2bf(a.w);
  A.u[4] = f2bf(b.x); A.u[5] = f2bf(b.y); A.u[6] = f2bf(b.z); A.u[7] = f2bf(b.w);
  return A.v;
}

// ---------------------------------------------------------------------------
// Cast fp32 -> bf16 for the 5 weight matrices. grid = 81.
// ---------------------------------------------------------------------------
__global__ __launch_bounds__(256) void cast_w(
    const float* __restrict__ qw, const float* __restrict__ kw,
    const float* __restrict__ fw, const float* __restrict__ hww,
    const float* __restrict__ pw,
    unsigned short* qwb, unsigned short* kwb, unsigned short* fwb,
    unsigned short* hwb, unsigned short* pwb) {
  const int blk = blockIdx.x;
  const float* s; unsigned short* d; int b0, nq;
  if      (blk < 16) { s = qw;  d = qwb; b0 = blk;      nq = 16384; }
  else if (blk < 32) { s = kw;  d = kwb; b0 = blk - 16; nq = 16384; }
  else if (blk < 49) { s = fw;  d = fwb; b0 = blk - 32; nq = 16640; }
  else if (blk < 65) { s = hww; d = hwb; b0 = blk - 49; nq = 16384; }
  else               { s = pw;  d = pwb; b0 = blk - 65; nq = 16384; }
  #pragma unroll
  for (int t = 0; t < 4; ++t) {
    const int q = b0*1024 + t*256 + threadIdx.x;
    if (q < nq) {
      float4 v = ((const float4*)s)[q];
      ushort4 o;
      o.x = f2bf(v.x); o.y = f2bf(v.y); o.z = f2bf(v.z); o.w = f2bf(v.w);
      ((ushort4*)d)[q] = o;
    }
  }
}

// ---------------------------------------------------------------------------
// MERGED q/k/f projections (one launch, 1056 blocks), bf16 weights.
// ---------------------------------------------------------------------------
__global__ __launch_bounds__(256) void fused_qkf(
    const float* __restrict__ lat, const float* __restrict__ ctx,
    const unsigned short* __restrict__ qw, const unsigned short* __restrict__ kw,
    const unsigned short* __restrict__ fw, const float* __restrict__ fb,
    unsigned short* __restrict__ q_bf, unsigned short* __restrict__ kpl,
    unsigned short* __restrict__ vctx, float* __restrict__ gates) {
  __shared__ unsigned short sh[256 * 68];   // 34 KB (f); k uses [64*264] of it
  const int blk = blockIdx.x;
  const int tid = threadIdx.x, w = tid >> 6, l = tid & 63;
  const int lr = l & 15, lk = l >> 4;

  if (blk < 32) {
    // ---------------- q projection ----------------
    const int r0 = blk * 64, rw = r0 + w*16;
    const float* ap = lat + (size_t)(rw + lr)*256 + lk*8;
    f32x4 acc[16];
    #pragma unroll
    for (int j = 0; j < 16; ++j) acc[j] = (f32x4){0.f,0.f,0.f,0.f};
    #pragma unroll
    for (int k0 = 0; k0 < 256; k0 += 32) {
      bf16x8 a = pack8(*(const float4*)(ap + k0), *(const float4*)(ap + k0 + 4));
      #pragma unroll
      for (int j = 0; j < 16; ++j) {
        bf16x8 b = *reinterpret_cast<const bf16x8*>(qw + (size_t)(j*16 + lr)*256 + k0 + lk*8);
        acc[j] = __builtin_amdgcn_mfma_f32_16x16x32_bf16(a, b, acc[j], 0, 0, 0);
      }
    }
    #pragma unroll
    for (int j = 0; j < 16; ++j)
      #pragma unroll
      for (int rr = 0; rr < 4; ++rr)
        q_bf[(size_t)(rw + lk*4 + rr)*256 + j*16 + lr] = f2bf(acc[j][rr]);
  } else if (blk < 544) {
    // ---------------- k projection (head-planar out) ----------------
    const int r0 = (blk - 32) * 64, rw = r0 + w*16;
    const float* ap = ctx + (size_t)(rw + lr)*256 + lk*8;
    f32x4 acc[16];
    #pragma unroll
    for (int j = 0; j < 16; ++j) acc[j] = (f32x4){0.f,0.f,0.f,0.f};
    #pragma unroll
    for (int k0 = 0; k0 < 256; k0 += 32) {
      bf16x8 a = pack8(*(const float4*)(ap + k0), *(const float4*)(ap + k0 + 4));
      #pragma unroll
      for (int j = 0; j < 16; ++j) {
        bf16x8 b = *reinterpret_cast<const bf16x8*>(kw + (size_t)(j*16 + lr)*256 + k0 + lk*8);
        acc[j] = __builtin_amdgcn_mfma_f32_16x16x32_bf16(a, b, acc[j], 0, 0, 0);
      }
    }
    #pragma unroll
    for (int j = 0; j < 16; ++j)
      #pragma unroll
      for (int rr = 0; rr < 4; ++rr)
        sh[(w*16 + lk*4 + rr)*264 + j*16 + lr] = f2bf(acc[j][rr]);
    __syncthreads();
    const int b = r0 >> 12, mm0 = r0 & 4095;
    #pragma unroll
    for (int it = 0; it < 8; ++it) {
      const int idx = it*256 + tid;
      const int ch = idx & 3, m = (idx >> 2) & 63, h = idx >> 8;
      uint4 v = *(const uint4*)&sh[m*264 + h*32 + ch*8];
      *(uint4*)&kpl[(((size_t)(b*8 + h))*4096 + mm0 + m)*32 + ch*8] = v;
    }
  } else {
    // ---------------- f projection ----------------
    const int r0 = (blk - 544) * 64, rw = r0 + w*16;
    const float* ap = ctx + (size_t)(rw + lr)*256 + lk*8;
    f32x4 acc[17];
    #pragma unroll
    for (int j = 0; j < 17; ++j) acc[j] = (f32x4){0.f,0.f,0.f,0.f};
    #pragma unroll
    for (int k0 = 0; k0 < 256; k0 += 32) {
      bf16x8 a = pack8(*(const float4*)(ap + k0), *(const float4*)(ap + k0 + 4));
      #pragma unroll
      for (int j = 0; j < 17; ++j) {
        const int n = j*16 + lr;
        bf16x8 b = {};
        if (n < 260)
          b = *reinterpret_cast<const bf16x8*>(fw + (size_t)n*256 + k0 + lk*8);
        acc[j] = __builtin_amdgcn_mfma_f32_16x16x32_bf16(a, b, acc[j], 0, 0, 0);
      }
    }
    const int hwl = w*16 + lk*4;
    #pragma unroll
    for (int j = 0; j < 16; ++j) {
      const float bb = fb[j*16 + lr];
      #pragma unroll
      for (int rr = 0; rr < 4; ++rr)
        sh[(j*16 + lr)*68 + hwl + rr] = f2bf(acc[j][rr] + bb);
    }
    {
      const int rbase = rw + lk*4;
      const int b = rbase >> 12, hw = rbase & 4095;
      if (lr < 4) {
        const float bb = fb[256 + lr];
        float4 o = make_float4(acc[16][0] + bb, acc[16][1] + bb,
                               acc[16][2] + bb, acc[16][3] + bb);
        *(float4*)&gates[((size_t)(b*4 + lr))*4096 + hw] = o;
      }
    }
    __syncthreads();
    const int b = r0 >> 12, hw0 = r0 & 4095;
    #pragma unroll
    for (int it = 0; it < 8; ++it) {
      const int idx = it*256 + tid;
      const int n = idx >> 3, ch = idx & 7;
      uint4 v = *(const uint4*)&sh[n*68 + ch*8];
      *(uint4*)&vctx[((size_t)(b*256 + n))*4096 + hw0 + ch*8] = v;
    }
  }
}

// ---------------------------------------------------------------------------
// FUSED depthwise conv chain, sliding-window form; bf16 in/out, in-place.
// grid = 2048.
// ---------------------------------------------------------------------------
__global__ __launch_bounds__(256) void fused_conv(
    const unsigned short* in, const float* __restrict__ wk3,
    const float* __restrict__ wk5, const float* __restrict__ wk7,
    const float* __restrict__ gates, unsigned short* out) {
  constexpr int TW = 70;
  __shared__ float A[TW * TW];
  __shared__ float w3[9];
  __shared__ float w5[25];
  __shared__ float w7[49];
  __shared__ float red[4];
  const int tid = threadIdx.x;
  const int b = blockIdx.x >> 8, c = blockIdx.x & 255;
  if (tid < 9)  w3[tid] = wk3[c*9  + tid];
  else if (tid < 34) w5[tid-9]  = wk5[c*25 + tid-9];
  else if (tid < 83) w7[tid-34] = wk7[c*49 + tid-34];
  const unsigned short* ip = in + (size_t)(b*256 + c) * 4096;
  for (int idx = tid; idx < TW*TW; idx += 256) {
    const int ty = idx / TW, tx = idx - ty*TW;
    const int gy = ty - 3, gx = tx - 3;
    A[idx] = (gy >= 0 && gy < 64 && gx >= 0 && gx < 64) ? bf2f(ip[gy*64 + gx]) : 0.0f;
  }
  __syncthreads();
  const int x = tid & 63, ys = (tid >> 6) * 16;
  const float* g0 = gates + (size_t)(b*4 + 0) * 4096;
  const float* g1 = gates + (size_t)(b*4 + 1) * 4096;
  const float* g2 = gates + (size_t)(b*4 + 2) * 4096;
  const float* g3 = gates + (size_t)(b*4 + 3) * 4096;
  float s[16], acc[16];
  // ---- conv3 (off=2) ----
  #pragma unroll
  for (int i = 0; i < 16; ++i) s[i] = 0.f;
  #pragma unroll
  for (int kx = 0; kx < 3; ++kx) {
    const float* col = &A[(ys + 2)*TW + x + 2 + kx];
    #pragma unroll
    for (int r = 0; r < 18; ++r) {
      const float v = col[r*TW];
      #pragma unroll
      for (int ky = 0; ky < 3; ++ky) {
        const int i = r - ky;
        if (i >= 0 && i < 16) s[i] += w3[ky*3 + kx] * v;
      }
    }
  }
  #pragma unroll
  for (int i = 0; i < 16; ++i) {
    s[i] = gelu_f(s[i]);
    acc[i] = s[i] * g0[(ys + i)*64 + x];
  }
  __syncthreads();
  #pragma unroll
  for (int i = 0; i < 16; ++i) A[(ys + i + 3)*TW + x + 3] = s[i];
  __syncthreads();
  // ---- conv5 (off=1) ----
  #pragma unroll
  for (int i = 0; i < 16; ++i) s[i] = 0.f;
  #pragma unroll
  for (int kx = 0; kx < 5; ++kx) {
    const float* col = &A[(ys + 1)*TW + x + 1 + kx];
    #pragma unroll
    for (int r = 0; r < 20; ++r) {
      const float v = col[r*TW];
      #pragma unroll
      for (int ky = 0; ky < 5; ++ky) {
        const int i = r - ky;
        if (i >= 0 && i < 16) s[i] += w5[ky*5 + kx] * v;
      }
    }
  }
  #pragma unroll
  for (int i = 0; i < 16; ++i) {
    s[i] = gelu_f(s[i]);
    acc[i] += s[i] * g1[(ys + i)*64 + x];
  }
  __syncthreads();
  #pragma unroll
  for (int i = 0; i < 16; ++i) A[(ys + i + 3)*TW + x + 3] = s[i];
  __syncthreads();
  // ---- conv7 (off=0) + mean ----
  #pragma unroll
  for (int i = 0; i < 16; ++i) s[i] = 0.f;
  #pragma unroll
  for (int kx = 0; kx < 7; ++kx) {
    const float* col = &A[ys*TW + x + kx];
    #pragma unroll
    for (int r = 0; r < 22; ++r) {
      const float v = col[r*TW];
      #pragma unroll
      for (int ky = 0; ky < 7; ++ky) {
        const int i = r - ky;
        if (i >= 0 && i < 16) s[i] += w7[ky*7 + kx] * v;
      }
    }
  }
  float msum = 0.f;
  #pragma unroll
  for (int i = 0; i < 16; ++i) {
    s[i] = gelu_f(s[i]);
    acc[i] += s[i] * g2[(ys + i)*64 + x];
    msum += s[i];
  }
  #pragma unroll
  for (int off = 32; off >= 1; off >>= 1) msum += __shfl_xor(msum, off, 64);
  if ((tid & 63) == 0) red[tid >> 6] = msum;
  __syncthreads();
  const float vg = gelu_f((red[0]+red[1]+red[2]+red[3]) * (1.0f/4096.0f));
  unsigned short* vp = out + (size_t)(b*256 + c) * 4096;
  #pragma unroll
  for (int i = 0; i < 16; ++i) {
    const int pix = (ys + i)*64 + x;
    vp[pix] = f2bf(acc[i] + vg * g3[pix]);
  }
}

// ---------------------------------------------------------------------------
// Full-depth MFMA h-GEMM (bf16 weights). grid (64, 8).
// ---------------------------------------------------------------------------
__global__ __launch_bounds__(256) void mfma_h(
    const unsigned short* __restrict__ vall, const unsigned short* __restrict__ hwb,
    const float* __restrict__ hb, unsigned short* __restrict__ vlin) {
  __shared__ unsigned short sh[256 * 72];
  const int hw0 = blockIdx.x * 64, b = blockIdx.y;
  const int tid = threadIdx.x, w = tid >> 6, l = tid & 63;
  const int lr = l & 15, lk = l >> 4;
  const int cl = tid >> 3, hl = (tid & 7) * 8;
  #pragma unroll
  for (int c0 = 0; c0 < 256; c0 += 32) {
    const unsigned short* sp = vall + (size_t)(b*256 + c0 + cl)*4096 + hw0 + hl;
    ushort4 u0 = *(const ushort4*)sp;
    ushort4 u1 = *(const ushort4*)(sp + 4);
    sh[(hl+0)*264 + c0+cl] = u0.x; sh[(hl+1)*264 + c0+cl] = u0.y;
    sh[(hl+2)*264 + c0+cl] = u0.z; sh[(hl+3)*264 + c0+cl] = u0.w;
    sh[(hl+4)*264 + c0+cl] = u1.x; sh[(hl+5)*264 + c0+cl] = u1.y;
    sh[(hl+6)*264 + c0+cl] = u1.z; sh[(hl+7)*264 + c0+cl] = u1.w;
  }
  __syncthreads();
  const int dw = w * 64;
  f32x4 acc[4][4];
  #pragma unroll
  for (int j2 = 0; j2 < 4; ++j2)
    #pragma unroll
    for (int j = 0; j < 4; ++j) acc[j2][j] = (f32x4){0.f,0.f,0.f,0.f};
  #pragma unroll
  for (int k0 = 0; k0 < 256; k0 += 32) {
    bf16x8 a[4];
    #pragma unroll
    for (int j2 = 0; j2 < 4; ++j2)
      a[j2] = *reinterpret_cast<const bf16x8*>(hwb + (size_t)(dw + j2*16 + lr)*256 + k0 + lk*8);
    #pragma unroll
    for (int j = 0; j < 4; ++j) {
      bf16x8 bv = *reinterpret_cast<const bf16x8*>(&sh[(j*16 + lr)*264 + k0 + lk*8]);
      #pragma unroll
      for (int j2 = 0; j2 < 4; ++j2)
        acc[j2][j] = __builtin_amdgcn_mfma_f32_16x16x32_bf16(a[j2], bv, acc[j2][j], 0, 0, 0);
    }
  }
  float hbv[4][4];
  #pragma unroll
  for (int j2 = 0; j2 < 4; ++j2)
    #pragma unroll
    for (int rr = 0; rr < 4; ++rr) hbv[j2][rr] = hb[dw + j2*16 + lk*4 + rr];
  __syncthreads();
  #pragma unroll
  for (int j2 = 0; j2 < 4; ++j2)
    #pragma unroll
    for (int j = 0; j < 4; ++j)
      #pragma unroll
      for (int rr = 0; rr < 4; ++rr)
        sh[(dw + j2*16 + lk*4 + rr)*72 + j*16 + lr] = f2bf(acc[j2][j][rr] + hbv[j2][rr]);
  __syncthreads();
  const int q = hw0 >> 8, dim0 = hw0 & 255;
  #pragma unroll
  for (int it = 0; it < 8; ++it) {
    const int dl = it*32 + (tid >> 3);
    const int ch = tid & 7;
    const int m = dl*16 + q;
    uint4 v = *(const uint4*)&sh[dl*72 + ch*8];
    *(uint4*)&vlin[((size_t)(b*4096 + m))*256 + dim0 + ch*8] = v;
  }
}

// ---------------------------------------------------------------------------
// bf16 transpose: v_tb[b][dim][m] from vlin[b][m][dim]. grid (64, 4, 8).
// ---------------------------------------------------------------------------
__global__ __launch_bounds__(256) void trans_bf(
    const unsigned short* __restrict__ vlin, unsigned short* __restrict__ vt) {
  __shared__ unsigned short T[64][72];
  const int tid = threadIdx.x;
  const int m0 = blockIdx.x * 64, d0 = blockIdx.y * 64, b = blockIdx.z;
  #pragma unroll
  for (int it = 0; it < 2; ++it) {
    const int ml = it*32 + (tid >> 3);
    const int ch = tid & 7;
    uint4 v = *(const uint4*)&vlin[((size_t)(b*4096 + m0 + ml))*256 + d0 + ch*8];
    *(uint4*)&T[ml][ch*8] = v;
  }
  __syncthreads();
  #pragma unroll
  for (int it = 0; it < 2; ++it) {
    const int dl = it*32 + (tid >> 3);
    const int ch = tid & 7;
    unsigned short tmp[8];
    #pragma unroll
    for (int k = 0; k < 8; ++k) tmp[k] = T[ch*8 + k][dl];
    *(uint4*)&vt[((size_t)(b*256 + d0 + dl))*4096 + m0 + ch*8] = *(uint4*)tmp;
  }
}

// ---------------------------------------------------------------------------
// FUSED attention + PV; K head-planar kpl[b][h][m][32]; nt attn stores.
// R15 structure (best measured): statically-paired even/odd pass-2 body,
// no runtime branch. Block = (bh, 16-row n-tile), 4 waves each own an
// m-quarter. grid = 1024.
// ---------------------------------------------------------------------------
__global__ __launch_bounds__(256) void attn_pv(
    const unsigned short* __restrict__ qb, const unsigned short* __restrict__ kpl,
    const unsigned short* __restrict__ vt, float* __restrict__ attn,
    unsigned short* __restrict__ aout) {
  const int blk = blockIdx.x;
  const int bh = blk & 63, nt = blk >> 6;
  const int b = bh >> 3, h = bh & 7;
  const int tid = threadIdx.x;
  const int w = tid >> 6, l = tid & 63;
  const int lr = l & 15, lk = l >> 4;
  const int n0 = nt * 16;
  __shared__ float rs[4][16];
  __shared__ unsigned short pl[4][16][40];
  __shared__ float ps[4][16][36];
  __shared__ float osum[4][16][32];
  bf16x8 aq = *reinterpret_cast<const bf16x8*>(
      qb + ((size_t)(b*256 + n0 + lr))*256 + h*32 + lk*8);
  const unsigned short* kbase = kpl + ((size_t)(b*8 + h))*4096*32 + lk*8;
  // pass 1: row sums
  float sum[4] = {0.f, 0.f, 0.f, 0.f};
  #pragma unroll 4
  for (int mt = 0; mt < 64; ++mt) {
    const int m0 = w*1024 + mt*16;
    bf16x8 bk = *reinterpret_cast<const bf16x8*>(kbase + (size_t)(m0 + lr)*32);
    f32x4 d = __builtin_amdgcn_mfma_f32_16x16x32_bf16(aq, bk, (f32x4){0.f,0.f,0.f,0.f}, 0, 0, 0);
    #pragma unroll
    for (int r = 0; r < 4; ++r) sum[r] += __expf(d[r] * CSCALE);
  }
  #pragma unroll
  for (int r = 0; r < 4; ++r) {
    #pragma unroll
    for (int m = 1; m < 16; m <<= 1) sum[r] += __shfl_xor(sum[r], m, 64);
  }
  if (lr == 0) {
    #pragma unroll
    for (int r = 0; r < 4; ++r) rs[w][lk*4 + r] = sum[r];
  }
  __syncthreads();
  float invS[4];
  #pragma unroll
  for (int r = 0; r < 4; ++r) {
    const int rowi = lk*4 + r;
    invS[r] = 1.0f / (rs[0][rowi] + rs[1][rowi] + rs[2][rowi] + rs[3][rowi]);
  }
  // pass 2: statically-paired QK + staged attn store (nt) + PV
  float* ab = attn + ((size_t)bh*256 + n0) * 4096;
  const unsigned short* vb = vt + ((size_t)(b*256 + h*32))*4096;
  const int fr = l >> 3;
  const int fm = (l & 7) * 4;
  f32x4 acc0 = {0.f,0.f,0.f,0.f}, acc1 = {0.f,0.f,0.f,0.f};
  #pragma unroll 2
  for (int mt2 = 0; mt2 < 32; ++mt2) {
    const int m0 = w*1024 + mt2*32;
    bf16x8 bk0 = *reinterpret_cast<const bf16x8*>(kbase + (size_t)(m0 + lr)*32);
    bf16x8 bk1 = *reinterpret_cast<const bf16x8*>(kbase + (size_t)(m0 + 16 + lr)*32);
    bf16x8 bv0 = *reinterpret_cast<const bf16x8*>(vb + (size_t)lr*4096 + m0 + lk*8);
    bf16x8 bv1 = *reinterpret_cast<const bf16x8*>(vb + (size_t)(16 + lr)*4096 + m0 + lk*8);
    f32x4 d0 = __builtin_amdgcn_mfma_f32_16x16x32_bf16(aq, bk0, (f32x4){0.f,0.f,0.f,0.f}, 0, 0, 0);
    f32x4 d1 = __builtin_amdgcn_mfma_f32_16x16x32_bf16(aq, bk1, (f32x4){0.f,0.f,0.f,0.f}, 0, 0, 0);
    #pragma unroll
    for (int r = 0; r < 4; ++r) {
      const float p0 = __expf(d0[r] * CSCALE) * invS[r];
      ps[w][lk*4 + r][lr]      = p0;
      pl[w][lk*4 + r][lr]      = f2bf(p0);
      const float p1 = __expf(d1[r] * CSCALE) * invS[r];
      ps[w][lk*4 + r][16 + lr] = p1;
      pl[w][lk*4 + r][16 + lr] = f2bf(p1);
    }
    bf16x8 pa = *reinterpret_cast<const bf16x8*>(&pl[w][lr][lk*8]);
    acc0 = __builtin_amdgcn_mfma_f32_16x16x32_bf16(pa, bv0, acc0, 0, 0, 0);
    acc1 = __builtin_amdgcn_mfma_f32_16x16x32_bf16(pa, bv1, acc1, 0, 0, 0);
    #pragma unroll
    for (int i = 0; i < 2; ++i) {
      const int row = i*8 + fr;
      f32x4 pv4 = *(const f32x4*)&ps[w][row][fm];
      __builtin_nontemporal_store(pv4, (f32x4*)&ab[(size_t)row*4096 + m0 + fm]);
    }
  }
  #pragma unroll
  for (int r = 0; r < 4; ++r) {
    osum[w][lk*4 + r][lr]      = acc0[r];
    osum[w][lk*4 + r][16 + lr] = acc1[r];
  }
  __syncthreads();
  for (int i = tid; i < 512; i += 256) {
    const int n = i >> 5, d = i & 31;
    const float s = osum[0][n][d] + osum[1][n][d] + osum[2][n][d] + osum[3][n][d];
    aout[((size_t)(b*256 + n0 + n))*256 + h*32 + d] = f2bf(s);
  }
}

// ---------------------------------------------------------------------------
// MFMA proj: out0[r][n] = aout[r][:] . proj_w[n][:] + proj_b[n] (bf16 W).
// grid (32, 4).
// ---------------------------------------------------------------------------
__global__ __launch_bounds__(256) void mfma_proj(
    const unsigned short* __restrict__ A, const unsigned short* __restrict__ W,
    const float* __restrict__ pb, float* __restrict__ out) {
  const int r0 = blockIdx.x * 64, n0 = blockIdx.y * 64;
  const int tid = threadIdx.x, w = tid >> 6, l = tid & 63;
  const int lr = l & 15, lk = l >> 4;
  const int rw = r0 + w*16;
  const unsigned short* ap = A + (size_t)(rw + lr)*256 + lk*8;
  f32x4 acc[4] = {{0.f,0.f,0.f,0.f},{0.f,0.f,0.f,0.f},{0.f,0.f,0.f,0.f},{0.f,0.f,0.f,0.f}};
  #pragma unroll
  for (int k0 = 0; k0 < 256; k0 += 32) {
    bf16x8 a = *reinterpret_cast<const bf16x8*>(ap + k0);
    #pragma unroll
    for (int j = 0; j < 4; ++j) {
      bf16x8 b = *reinterpret_cast<const bf16x8*>(W + (size_t)(n0 + j*16 + lr)*256 + k0 + lk*8);
      acc[j] = __builtin_amdgcn_mfma_f32_16x16x32_bf16(a, b, acc[j], 0, 0, 0);
    }
  }
  #pragma unroll
  for (int j = 0; j < 4; ++j) {
    const int n = n0 + j*16 + lr;
    const float bb = pb[n];
    #pragma unroll
    for (int rr = 0; rr < 4; ++rr)
      out[(size_t)(rw + lk*4 + rr)*256 + n] = acc[j][rr] + bb;
  }
}

} // namespace

extern "C" void kernel_launch(void* const* d_in, const int* in_sizes, int n_in,
                              void* d_out, int out_size, void* d_ws, size_t ws_size,
                              hipStream_t stream) {
  (void)in_sizes; (void)n_in; (void)out_size; (void)ws_size;
  const float* latents = (const float*)d_in[0];
  const float* context = (const float*)d_in[1];
  const float* q_w    = (const float*)d_in[2];
  const float* k_w    = (const float*)d_in[3];
  const float* f_w    = (const float*)d_in[4];
  const float* f_b    = (const float*)d_in[5];
  const float* h_w    = (const float*)d_in[6];
  const float* h_b    = (const float*)d_in[7];
  const float* fk0    = (const float*)d_in[8];
  const float* fk1    = (const float*)d_in[9];
  const float* fk2    = (const float*)d_in[10];
  const float* proj_w = (const float*)d_in[11];
  const float* proj_b = (const float*)d_in[12];

  float* out0 = (float*)d_out;                  // (8,256,256)
  float* attn = out0 + (size_t)8*256*256;       // (8,8,256,4096)

  // workspace layout (byte offsets), total ~70 MB
  char* w = (char*)d_ws;
  unsigned short* vcv     = (unsigned short*)(w + 0x0);        // 16 MB vctx/vall (in-place conv)
  unsigned short* kpl     = (unsigned short*)(w + 0x1000000);  // 16 MB (8,8,4096,32) head-planar K
  unsigned short* v_tb    = (unsigned short*)(w + 0x2000000);  // 16 MB (8,256,4096) vT[dim][m]
  unsigned short* vlin_bf = (unsigned short*)(w + 0x3000000);  // 16 MB (8,4096,256) [m][dim]
  unsigned short* q_bf    = (unsigned short*)(w + 0x4000000);  //  1 MB (8,256,256)
  unsigned short* aout_bf = (unsigned short*)(w + 0x4100000);  //  1 MB
  unsigned short* qw_bf   = (unsigned short*)(w + 0x4200000);  // 128 KB
  unsigned short* kw_bf   = (unsigned short*)(w + 0x4220000);  // 128 KB
  unsigned short* fw_bf   = (unsigned short*)(w + 0x4240000);  // 130 KB
  unsigned short* hw_bf   = (unsigned short*)(w + 0x4270000);  // 128 KB
  unsigned short* pw_bf   = (unsigned short*)(w + 0x4290000);  // 128 KB
  float*          gates   = (float*)(w + 0x42B0000);           // 512 KB fp32

  cast_w    <<<81, 256, 0, stream>>>(q_w, k_w, f_w, h_w, proj_w,
                                     qw_bf, kw_bf, fw_bf, hw_bf, pw_bf);
  fused_qkf <<<1056, 256, 0, stream>>>(latents, context, qw_bf, kw_bf, fw_bf,
                                       f_b, q_bf, kpl, vcv, gates);
  fused_conv<<<2048, 256, 0, stream>>>(vcv, fk0, fk1, fk2, gates, vcv);
  mfma_h    <<<dim3(64, 8), 256, 0, stream>>>(vcv, hw_bf, h_b, vlin_bf);
  trans_bf  <<<dim3(64, 4, 8), 256, 0, stream>>>(vlin_bf, v_tb);
  attn_pv   <<<1024, 256, 0, stream>>>(q_bf, kpl, v_tb, attn, aout_bf);
  mfma_proj <<<dim3(32, 4), 256, 0, stream>>>(aout_bf, pw_bf, proj_b, out0);
}